// Round 1
// baseline (4057.695 us; speedup 1.0000x reference)
//
#include <hip/hip_runtime.h>
#include <hip/hip_bf16.h>
#include <hip/hip_cooperative_groups.h>

namespace cg = cooperative_groups;

typedef __attribute__((ext_vector_type(8))) short short8;
typedef __attribute__((ext_vector_type(4))) float floatx4;

#define Bb 64
#define Ii 48
#define Oo 48
#define Ff 256
#define Hh 256
#define NG 1280      // 5*H
#define KK 512       // 2F (Wx rows) == 2H (Ws rows)
#define ND 95        // I+O-1 diagonals
#define CHUNK 80     // reordered cols per wg = 16 h * 5 gates
#define NH 16        // h-values per chunk
#define HCHUNKS 16   // 1280/80
#define GROUPS 16
#define CPG 3        // cells per group (GROUPS*CPG = 48 = max diagonal)
#define WLDS_STRIDE 520      // 512 + 8 pad: per-col k-stride -> 2-way (free) LDS conflicts
#define WLDS_STRIDE_PRE 264  // 256 + 8 pad
#define DSTRIDE 84           // 80 + 4 pad for D staging

// ---------------- pack / cast kernel ----------------
// Wxp/Wsp: [n'][k] bf16, column-major-packed so B-fragments (8 consecutive k at
// fixed col) are one 16B load. n' = gate-interleaved reorder: orig = (n'%5)*H + n'/5.
// xb/yb: [i][b][f] bf16 (row m = i*64+b contiguous in f for A-fragments).
__global__ __launch_bounds__(256) void pack_kernel(
    const float* __restrict__ Wx, const float* __restrict__ Ws,
    const float* __restrict__ x, const float* __restrict__ y,
    __hip_bfloat16* __restrict__ Wxp, __hip_bfloat16* __restrict__ Wsp,
    __hip_bfloat16* __restrict__ xb, __hip_bfloat16* __restrict__ yb) {
  int idx = blockIdx.x * blockDim.x + threadIdx.x;
  int stride = gridDim.x * blockDim.x;
  int total_w = NG * KK;
  for (int t = idx; t < total_w; t += stride) {
    int np = t / KK, k = t % KK;
    int orig = (np % 5) * Hh + (np / 5);
    Wxp[t] = __float2bfloat16(Wx[k * NG + orig]);
    Wsp[t] = __float2bfloat16(Ws[k * NG + orig]);
  }
  int total_x = Bb * Ii * Ff;
  for (int t = idx; t < total_x; t += stride) {
    int f = t % Ff; int rest = t / Ff; int b = rest % Bb; int i = rest / Bb;
    xb[(i * Bb + b) * Ff + f] = __float2bfloat16(x[(b * Ii + i) * Ff + f]);
    yb[(i * Bb + b) * Ff + f] = __float2bfloat16(y[(b * Oo + i) * Ff + f]);
  }
}

// ---------------- precompute GEMM: Px[i][b][n'], Py[j][b][n'] ----------------
// grid = 2 * 48 * 16 wgs; wg tile = 64 rows x 80 reordered cols, K=256.
__global__ __launch_bounds__(256) void pregemm(
    const __hip_bfloat16* __restrict__ xb, const __hip_bfloat16* __restrict__ yb,
    const __hip_bfloat16* __restrict__ Wxp,
    float* __restrict__ Px, float* __restrict__ Py) {
  __shared__ __hip_bfloat16 Wl[CHUNK * WLDS_STRIDE_PRE];
  int wg = blockIdx.x;
  int isY = wg >= (Ii * HCHUNKS);
  int w = isY ? wg - Ii * HCHUNKS : wg;
  int mblk = w >> 4;          // i (or j)
  int hc = w & 15;
  int n0 = hc * CHUNK;
  int koff = isY ? Ff : 0;    // Py uses Wx rows [F, 2F)
  int tid = threadIdx.x;
  // stage 80 cols x 256 k of Wxp into LDS
  for (int idx = tid; idx < CHUNK * (Ff / 8); idx += 256) {
    int cl = idx >> 5;                 // 32 8-wide pieces per col
    int kb = (idx & 31) << 3;
    *(short8*)&Wl[cl * WLDS_STRIDE_PRE + kb] =
        *(const short8*)&Wxp[(n0 + cl) * KK + koff + kb];
  }
  __syncthreads();
  int wave = tid >> 6, lane = tid & 63;
  int lr = lane & 15, q = lane >> 4;
  const __hip_bfloat16* Arow = (isY ? yb : xb) + ((size_t)mblk * Bb + wave * 16 + lr) * Ff;
  floatx4 acc[5];
#pragma unroll
  for (int t = 0; t < 5; t++) acc[t] = (floatx4){0.f, 0.f, 0.f, 0.f};
#pragma unroll
  for (int ks = 0; ks < Ff / 32; ks++) {
    int k = ks * 32 + q * 8;
    short8 a = *(const short8*)(Arow + k);
#pragma unroll
    for (int t = 0; t < 5; t++) {
      short8 bfr = *(const short8*)&Wl[(t * 16 + lr) * WLDS_STRIDE_PRE + k];
      acc[t] = __builtin_amdgcn_mfma_f32_16x16x32_bf16(a, bfr, acc[t], 0, 0, 0);
    }
  }
  float* Pr = (isY ? Py : Px) + (size_t)mblk * Bb * NG + n0;
#pragma unroll
  for (int t = 0; t < 5; t++)
#pragma unroll
    for (int r = 0; r < 4; r++)
      Pr[(wave * 16 + q * 4 + r) * NG + t * 16 + lr] = acc[t][r];
}

// ---------------- cooperative recurrent kernel ----------------
// 256 wgs = 16 groups x 16 hchunks. Each wg persists its Ws slice (80x512 bf16)
// in LDS for all 95 diagonals. Per diagonal, group g handles cells g, g+16, g+32.
__global__ __launch_bounds__(256) void lstm_coop(
    const float* __restrict__ Px, const float* __restrict__ Py,
    const float* __restrict__ bias, const __hip_bfloat16* __restrict__ Wsp,
    __hip_bfloat16* __restrict__ S0, __hip_bfloat16* __restrict__ S1,
    float* __restrict__ C0, float* __restrict__ C1,
    float* __restrict__ out) {
  cg::grid_group grid = cg::this_grid();
  __shared__ __hip_bfloat16 Wl[CHUNK * WLDS_STRIDE];  // 83,200 B
  __shared__ float Dl[Bb * DSTRIDE];                  // 21,504 B
  int wg = blockIdx.x;
  int group = wg >> 4;
  int hc = wg & 15;
  int n0 = hc * CHUNK;
  int h0 = hc * NH;
  int tid = threadIdx.x;
  int wave = tid >> 6, lane = tid & 63;
  int lr = lane & 15, q = lane >> 4;

  // persistent Ws slice: 80 cols x 512 k
  for (int idx = tid; idx < CHUNK * (KK / 8); idx += 256) {
    int cl = idx >> 6;                 // 64 8-wide pieces per col
    int kb = (idx & 63) << 3;
    *(short8*)&Wl[cl * WLDS_STRIDE + kb] = *(const short8*)&Wsp[(n0 + cl) * KK + kb];
  }
  __syncthreads();

  for (int d = 0; d < ND; d++) {
    int ilo = d - (Oo - 1); if (ilo < 0) ilo = 0;
    int ihi = d < Ii - 1 ? d : Ii - 1;
    int nd = ihi - ilo + 1;
    const __hip_bfloat16* Sprev = (d & 1) ? S1 : S0;
    __hip_bfloat16* Scur = (d & 1) ? S0 : S1;
    const float* Cprev = (d & 1) ? C1 : C0;
    float* Ccur = (d & 1) ? C0 : C1;
#pragma unroll 1
    for (int cc = 0; cc < CPG; cc++) {
      int ci = cc * GROUPS + group;   // round-robin for edge-diagonal balance
      if (ci < nd) {
        int i = ilo + ci;
        int j = d - i;
        // ---- GEMM: (64 x 512) @ (512 x 80) ----
        // buffer row 0 is the permanent zero row; actual row i lives at i+1.
        // s_hor = S[(i-1)+1] = row i ; s_ver = S[i+1].
        const __hip_bfloat16* Ah = Sprev + ((size_t)i * Bb + wave * 16 + lr) * Hh;
        const __hip_bfloat16* Av = Ah + (size_t)Bb * Hh;
        floatx4 acc[5];
#pragma unroll
        for (int t = 0; t < 5; t++) acc[t] = (floatx4){0.f, 0.f, 0.f, 0.f};
#pragma unroll
        for (int ks = 0; ks < KK / 32; ks++) {
          int k = ks * 32 + q * 8;
          short8 a = (k < Hh) ? *(const short8*)(Ah + k)
                              : *(const short8*)(Av + (k - Hh));
#pragma unroll
          for (int t = 0; t < 5; t++) {
            short8 bfr = *(const short8*)&Wl[(t * 16 + lr) * WLDS_STRIDE + k];
            acc[t] = __builtin_amdgcn_mfma_f32_16x16x32_bf16(a, bfr, acc[t], 0, 0, 0);
          }
        }
        // ---- stage D (C-layout: col=lane&15, row=(lane>>4)*4+r) to LDS ----
#pragma unroll
        for (int t = 0; t < 5; t++)
#pragma unroll
          for (int r = 0; r < 4; r++)
            Dl[(wave * 16 + q * 4 + r) * DSTRIDE + t * 16 + lr] = acc[t][r];
        __syncthreads();
        // ---- elementwise LSTM update: 64 b x 16 h ----
        const float* PxR = Px + (size_t)i * Bb * NG + n0;
        const float* PyR = Py + (size_t)j * Bb * NG + n0;
        size_t rowOff = (size_t)(i + 1) * Bb * Hh;   // buffer row i+1
        for (int p = tid; p < Bb * NH; p += 256) {
          int hl = p & 15, b = p >> 4;
          int h = h0 + hl;
          int base = b * NG + 5 * hl;
          float pre[5];
#pragma unroll
          for (int g = 0; g < 5; g++)
            pre[g] = Dl[b * DSTRIDE + 5 * hl + g] + PxR[base + g] + PyR[base + g]
                   + bias[g * Hh + h];
          float c_h = Cprev[rowOff - (size_t)Bb * Hh + b * Hh + h];  // (i-1, j)
          float c_v = Cprev[rowOff + b * Hh + h];                    // (i, j-1)
          float ig = 1.f / (1.f + __expf(-pre[0]));
          float fg = 1.f / (1.f + __expf(-pre[1]));
          float og = 1.f / (1.f + __expf(-pre[2]));
          float lg = 1.f / (1.f + __expf(-pre[3]));
          float gg = 1.f - 2.f / (__expf(2.f * pre[4]) + 1.f);       // tanh
          float cn = fg * (lg * c_h + (1.f - lg) * c_v) + ig * gg;
          float tc = 1.f - 2.f / (__expf(2.f * cn) + 1.f);
          float sn = og * tc;
          Ccur[rowOff + b * Hh + h] = cn;
          Scur[rowOff + b * Hh + h] = __float2bfloat16(sn);
          out[(((size_t)i * Oo + j) * Bb + b) * Hh + h] = sn;
        }
        __syncthreads();  // protect Dl before next cell reuses it
      }
    }
    grid.sync();
  }
}

// ---------------- host ----------------
extern "C" void kernel_launch(void* const* d_in, const int* in_sizes, int n_in,
                              void* d_out, int out_size, void* d_ws, size_t ws_size,
                              hipStream_t stream) {
  const float* x    = (const float*)d_in[0];
  const float* y    = (const float*)d_in[1];
  const float* Wx   = (const float*)d_in[2];
  const float* Ws   = (const float*)d_in[3];
  const float* bias = (const float*)d_in[4];
  float* out = (float*)d_out;

  char* ws = (char*)d_ws;
  size_t off = 0;
  auto alloc = [&](size_t bytes) -> void* {
    void* p = ws + off;
    off += (bytes + 255) & ~(size_t)255;
    return p;
  };
  __hip_bfloat16* Wxp = (__hip_bfloat16*)alloc((size_t)NG * KK * 2);
  __hip_bfloat16* Wsp = (__hip_bfloat16*)alloc((size_t)NG * KK * 2);
  __hip_bfloat16* xb  = (__hip_bfloat16*)alloc((size_t)Ii * Bb * Ff * 2);
  __hip_bfloat16* yb  = (__hip_bfloat16*)alloc((size_t)Oo * Bb * Ff * 2);
  float* Px = (float*)alloc((size_t)Ii * Bb * NG * 4);
  float* Py = (float*)alloc((size_t)Oo * Bb * NG * 4);
  char* stateBase = ws + off;
  __hip_bfloat16* S0 = (__hip_bfloat16*)alloc((size_t)(Ii + 1) * Bb * Hh * 2);
  __hip_bfloat16* S1 = (__hip_bfloat16*)alloc((size_t)(Ii + 1) * Bb * Hh * 2);
  float* C0 = (float*)alloc((size_t)(Ii + 1) * Bb * Hh * 4);
  float* C1 = (float*)alloc((size_t)(Ii + 1) * Bb * Hh * 4);
  size_t stateBytes = (size_t)((ws + off) - stateBase);

  // states must start at zero every call (ws is re-poisoned to 0xAA)
  hipMemsetAsync(stateBase, 0, stateBytes, stream);

  hipLaunchKernelGGL(pack_kernel, dim3(512), dim3(256), 0, stream,
                     Wx, Ws, x, y, Wxp, Wsp, xb, yb);
  hipLaunchKernelGGL(pregemm, dim3(2 * Ii * HCHUNKS), dim3(256), 0, stream,
                     xb, yb, Wxp, Px, Py);

  void* args[] = {(void*)&Px, (void*)&Py, (void*)&bias, (void*)&Wsp,
                  (void*)&S0, (void*)&S1, (void*)&C0, (void*)&C1, (void*)&out};
  hipLaunchCooperativeKernel((void*)lstm_coop, dim3(GROUPS * HCHUNKS), dim3(256),
                             args, 0, stream);
}

// Round 2
// 3466.987 us; speedup vs baseline: 1.1704x; 1.1704x over previous
//
#include <hip/hip_runtime.h>
#include <hip/hip_bf16.h>

typedef __attribute__((ext_vector_type(8))) short short8;
typedef __attribute__((ext_vector_type(4))) float floatx4;

#define Bb 64
#define Ii 48
#define Oo 48
#define Ff 256
#define Hh 256
#define NG 1280      // 5*H
#define KK 512       // 2F (Wx rows) == 2H (Ws rows)
#define ND 95        // I+O-1 diagonals
#define CHUNK 80     // reordered cols per wg = 16 h * 5 gates
#define NH 16        // h-values per chunk
#define HCHUNKS 16   // 1280/80
#define GROUPS 16
#define CPG 3        // cells per group (GROUPS*CPG = 48 = max diagonal)
#define WLDS_STRIDE 520      // 512 + 8 pad
#define WLDS_STRIDE_PRE 264  // 256 + 8 pad
#define DSTRIDE 84           // 80 + 4 pad for D staging

// ---------------- pack / cast kernel ----------------
__global__ __launch_bounds__(256) void pack_kernel(
    const float* __restrict__ Wx, const float* __restrict__ Ws,
    const float* __restrict__ x, const float* __restrict__ y,
    __hip_bfloat16* __restrict__ Wxp, __hip_bfloat16* __restrict__ Wsp,
    __hip_bfloat16* __restrict__ xb, __hip_bfloat16* __restrict__ yb) {
  int idx = blockIdx.x * blockDim.x + threadIdx.x;
  int stride = gridDim.x * blockDim.x;
  int total_w = NG * KK;
  for (int t = idx; t < total_w; t += stride) {
    int np = t / KK, k = t % KK;
    int orig = (np % 5) * Hh + (np / 5);
    Wxp[t] = __float2bfloat16(Wx[k * NG + orig]);
    Wsp[t] = __float2bfloat16(Ws[k * NG + orig]);
  }
  int total_x = Bb * Ii * Ff;
  for (int t = idx; t < total_x; t += stride) {
    int f = t % Ff; int rest = t / Ff; int b = rest % Bb; int i = rest / Bb;
    xb[(i * Bb + b) * Ff + f] = __float2bfloat16(x[(b * Ii + i) * Ff + f]);
    yb[(i * Bb + b) * Ff + f] = __float2bfloat16(y[(b * Oo + i) * Ff + f]);
  }
}

// ---------------- precompute GEMM: Px[i][b][n'], Py[j][b][n'] ----------------
__global__ __launch_bounds__(256) void pregemm(
    const __hip_bfloat16* __restrict__ xb, const __hip_bfloat16* __restrict__ yb,
    const __hip_bfloat16* __restrict__ Wxp,
    float* __restrict__ Px, float* __restrict__ Py) {
  __shared__ __hip_bfloat16 Wl[CHUNK * WLDS_STRIDE_PRE];
  int wg = blockIdx.x;
  int isY = wg >= (Ii * HCHUNKS);
  int w = isY ? wg - Ii * HCHUNKS : wg;
  int mblk = w >> 4;
  int hc = w & 15;
  int n0 = hc * CHUNK;
  int koff = isY ? Ff : 0;
  int tid = threadIdx.x;
  for (int idx = tid; idx < CHUNK * (Ff / 8); idx += 256) {
    int cl = idx >> 5;
    int kb = (idx & 31) << 3;
    *(short8*)&Wl[cl * WLDS_STRIDE_PRE + kb] =
        *(const short8*)&Wxp[(n0 + cl) * KK + koff + kb];
  }
  __syncthreads();
  int wave = tid >> 6, lane = tid & 63;
  int lr = lane & 15, q = lane >> 4;
  const __hip_bfloat16* Arow = (isY ? yb : xb) + ((size_t)mblk * Bb + wave * 16 + lr) * Ff;
  floatx4 acc[5];
#pragma unroll
  for (int t = 0; t < 5; t++) acc[t] = (floatx4){0.f, 0.f, 0.f, 0.f};
#pragma unroll
  for (int ks = 0; ks < Ff / 32; ks++) {
    int k = ks * 32 + q * 8;
    short8 a = *(const short8*)(Arow + k);
#pragma unroll
    for (int t = 0; t < 5; t++) {
      short8 bfr = *(const short8*)&Wl[(t * 16 + lr) * WLDS_STRIDE_PRE + k];
      acc[t] = __builtin_amdgcn_mfma_f32_16x16x32_bf16(a, bfr, acc[t], 0, 0, 0);
    }
  }
  float* Pr = (isY ? Py : Px) + (size_t)mblk * Bb * NG + n0;
#pragma unroll
  for (int t = 0; t < 5; t++)
#pragma unroll
    for (int r = 0; r < 4; r++)
      Pr[(wave * 16 + q * 4 + r) * NG + t * 16 + lr] = acc[t][r];
}

// ---------------- point-to-point spin-wait ----------------
__device__ __forceinline__ void wait16(const int* p) {
  while (__hip_atomic_load(p, __ATOMIC_RELAXED, __HIP_MEMORY_SCOPE_AGENT) < HCHUNKS)
    __builtin_amdgcn_s_sleep(2);
}

// ---------------- cooperative recurrent kernel (p2p dataflow) ----------------
// 256 wgs = 16 groups x 16 hchunks. Ws slice persistent in LDS. No grid barrier:
// per-cell done counters (16 wg-increments each). Cell (i,j) waits on
// (i-1,j), (i,j-1) [data deps] and (i+1,j-2) [WAR: ping-pong row-slot reuse].
__global__ __launch_bounds__(256) void lstm_coop(
    const float* __restrict__ Px, const float* __restrict__ Py,
    const float* __restrict__ bias, const __hip_bfloat16* __restrict__ Wsp,
    __hip_bfloat16* __restrict__ S0, __hip_bfloat16* __restrict__ S1,
    float* __restrict__ C0, float* __restrict__ C1,
    float* __restrict__ out, int* __restrict__ done) {
  __shared__ __hip_bfloat16 Wl[CHUNK * WLDS_STRIDE];  // 83,200 B
  __shared__ float Dl[Bb * DSTRIDE];                  // 21,504 B
  int wg = blockIdx.x;
  int group = wg >> 4;
  int hc = wg & 15;
  int n0 = hc * CHUNK;
  int h0 = hc * NH;
  int tid = threadIdx.x;
  int wave = tid >> 6, lane = tid & 63;
  int lr = lane & 15, q = lane >> 4;
  int hl = tid & 15;            // fixed h-lane for elementwise phase
  int brow0 = tid >> 4;         // b for elementwise iter 0 (+16 per iter)

  // persistent Ws slice: 80 cols x 512 k
  for (int idx = tid; idx < CHUNK * (KK / 8); idx += 256) {
    int cl = idx >> 6;
    int kb = (idx & 63) << 3;
    *(short8*)&Wl[cl * WLDS_STRIDE + kb] = *(const short8*)&Wsp[(n0 + cl) * KK + kb];
  }
  // per-thread bias (h fixed per thread)
  float bv[5];
#pragma unroll
  for (int g = 0; g < 5; g++) bv[g] = bias[g * Hh + h0 + hl];
  __syncthreads();

  for (int d = 0; d < ND; d++) {
    int ilo = d - (Oo - 1); if (ilo < 0) ilo = 0;
    int ihi = d < Ii - 1 ? d : Ii - 1;
    int nd = ihi - ilo + 1;
    const __hip_bfloat16* Sprev = (d & 1) ? S1 : S0;
    __hip_bfloat16* Scur = (d & 1) ? S0 : S1;
    const float* Cprev = (d & 1) ? C1 : C0;
    float* Ccur = (d & 1) ? C0 : C1;
#pragma unroll 1
    for (int cc = 0; cc < CPG; cc++) {
      int ci = cc * GROUPS + group;   // round-robin for edge-diagonal balance
      if (ci < nd) {
        int i = ilo + ci;
        int j = d - i;
        // ---- prefetch immutable per-cell operands BEFORE the spin ----
        const float* PxR = Px + (size_t)i * Bb * NG + n0;
        const float* PyR = Py + (size_t)j * Bb * NG + n0;
        float pxv[4][5], pyv[4][5];
#pragma unroll
        for (int it = 0; it < 4; it++) {
          int base = (brow0 + 16 * it) * NG + 5 * hl;
#pragma unroll
          for (int g = 0; g < 5; g++) {
            pxv[it][g] = PxR[base + g];
            pyv[it][g] = PyR[base + g];
          }
        }
        // ---- wait for producers (+ WAR guard), then acquire ----
        if (i > 0)              wait16(done + (i - 1) * Oo + j);
        if (j > 0)              wait16(done + i * Oo + (j - 1));
        if (i + 1 < Ii && j >= 2) wait16(done + (i + 1) * Oo + (j - 2));
        __builtin_amdgcn_fence(__ATOMIC_ACQUIRE, "agent");
        // ---- prefetch C-state (now safe), overlaps with GEMM ----
        size_t rowOff = (size_t)(i + 1) * Bb * Hh;
        float ch[4], cv[4];
#pragma unroll
        for (int it = 0; it < 4; it++) {
          int b = brow0 + 16 * it;
          ch[it] = Cprev[rowOff - (size_t)Bb * Hh + b * Hh + h0 + hl];
          cv[it] = Cprev[rowOff + b * Hh + h0 + hl];
        }
        // ---- GEMM: (64 x 512) @ (512 x 80) ----
        const __hip_bfloat16* Ah = Sprev + ((size_t)i * Bb + wave * 16 + lr) * Hh;
        const __hip_bfloat16* Av = Ah + (size_t)Bb * Hh;
        floatx4 acc[5];
#pragma unroll
        for (int t = 0; t < 5; t++) acc[t] = (floatx4){0.f, 0.f, 0.f, 0.f};
#pragma unroll
        for (int ks = 0; ks < KK / 32; ks++) {
          int k = ks * 32 + q * 8;
          short8 a = (k < Hh) ? *(const short8*)(Ah + k)
                              : *(const short8*)(Av + (k - Hh));
#pragma unroll
          for (int t = 0; t < 5; t++) {
            short8 bfr = *(const short8*)&Wl[(t * 16 + lr) * WLDS_STRIDE + k];
            acc[t] = __builtin_amdgcn_mfma_f32_16x16x32_bf16(a, bfr, acc[t], 0, 0, 0);
          }
        }
        // ---- stage D (C-layout: col=lane&15, row=(lane>>4)*4+r) to LDS ----
#pragma unroll
        for (int t = 0; t < 5; t++)
#pragma unroll
          for (int r = 0; r < 4; r++)
            Dl[(wave * 16 + q * 4 + r) * DSTRIDE + t * 16 + lr] = acc[t][r];
        __syncthreads();
        // ---- elementwise LSTM update: 64 b x 16 h (all operands in regs/LDS) ----
#pragma unroll
        for (int it = 0; it < 4; it++) {
          int b = brow0 + 16 * it;
          float pre[5];
#pragma unroll
          for (int g = 0; g < 5; g++)
            pre[g] = Dl[b * DSTRIDE + 5 * hl + g] + pxv[it][g] + pyv[it][g] + bv[g];
          float ig = 1.f / (1.f + __expf(-pre[0]));
          float fg = 1.f / (1.f + __expf(-pre[1]));
          float og = 1.f / (1.f + __expf(-pre[2]));
          float lg = 1.f / (1.f + __expf(-pre[3]));
          float gg = 1.f - 2.f / (__expf(2.f * pre[4]) + 1.f);   // tanh
          float cn = fg * (lg * ch[it] + (1.f - lg) * cv[it]) + ig * gg;
          float tc = 1.f - 2.f / (__expf(2.f * cn) + 1.f);
          float sn = og * tc;
          int h = h0 + hl;
          Ccur[rowOff + b * Hh + h] = cn;
          Scur[rowOff + b * Hh + h] = __float2bfloat16(sn);
          out[(((size_t)i * Oo + j) * Bb + b) * Hh + h] = sn;
        }
        // ---- publish: all wg stores done -> release -> bump cell counter ----
        __syncthreads();
        if (tid == 0) {
          __threadfence();   // agent-scope release (drains + L2 writeback/inv)
          atomicAdd(done + i * Oo + j, 1);
        }
      }
    }
  }
}

// ---------------- host ----------------
extern "C" void kernel_launch(void* const* d_in, const int* in_sizes, int n_in,
                              void* d_out, int out_size, void* d_ws, size_t ws_size,
                              hipStream_t stream) {
  const float* x    = (const float*)d_in[0];
  const float* y    = (const float*)d_in[1];
  const float* Wx   = (const float*)d_in[2];
  const float* Ws   = (const float*)d_in[3];
  const float* bias = (const float*)d_in[4];
  float* out = (float*)d_out;

  char* ws = (char*)d_ws;
  size_t off = 0;
  auto alloc = [&](size_t bytes) -> void* {
    void* p = ws + off;
    off += (bytes + 255) & ~(size_t)255;
    return p;
  };
  __hip_bfloat16* Wxp = (__hip_bfloat16*)alloc((size_t)NG * KK * 2);
  __hip_bfloat16* Wsp = (__hip_bfloat16*)alloc((size_t)NG * KK * 2);
  __hip_bfloat16* xb  = (__hip_bfloat16*)alloc((size_t)Ii * Bb * Ff * 2);
  __hip_bfloat16* yb  = (__hip_bfloat16*)alloc((size_t)Oo * Bb * Ff * 2);
  float* Px = (float*)alloc((size_t)Ii * Bb * NG * 4);
  float* Py = (float*)alloc((size_t)Oo * Bb * NG * 4);
  char* stateBase = ws + off;
  __hip_bfloat16* S0 = (__hip_bfloat16*)alloc((size_t)(Ii + 1) * Bb * Hh * 2);
  __hip_bfloat16* S1 = (__hip_bfloat16*)alloc((size_t)(Ii + 1) * Bb * Hh * 2);
  float* C0 = (float*)alloc((size_t)(Ii + 1) * Bb * Hh * 4);
  float* C1 = (float*)alloc((size_t)(Ii + 1) * Bb * Hh * 4);
  int*   done = (int*)alloc((size_t)Ii * Oo * 4);
  size_t stateBytes = (size_t)((ws + off) - stateBase);

  // states + flags must start at zero every call (ws is re-poisoned to 0xAA)
  hipMemsetAsync(stateBase, 0, stateBytes, stream);

  hipLaunchKernelGGL(pack_kernel, dim3(512), dim3(256), 0, stream,
                     Wx, Ws, x, y, Wxp, Wsp, xb, yb);
  hipLaunchKernelGGL(pregemm, dim3(2 * Ii * HCHUNKS), dim3(256), 0, stream,
                     xb, yb, Wxp, Px, Py);

  void* args[] = {(void*)&Px, (void*)&Py, (void*)&bias, (void*)&Wsp,
                  (void*)&S0, (void*)&S1, (void*)&C0, (void*)&C1,
                  (void*)&out, (void*)&done};
  hipLaunchCooperativeKernel((void*)lstm_coop, dim3(GROUPS * HCHUNKS), dim3(256),
                             args, 0, stream);
}

// Round 3
// 1716.563 us; speedup vs baseline: 2.3638x; 2.0197x over previous
//
#include <hip/hip_runtime.h>
#include <hip/hip_bf16.h>

typedef __attribute__((ext_vector_type(8))) short short8;
typedef __attribute__((ext_vector_type(4))) float floatx4;

#define Bb 64
#define Ii 48
#define Oo 48
#define Ff 256
#define Hh 256
#define NG 1280      // 5*H
#define KK 512       // 2F (Wx rows) == 2H (Ws rows)
#define CHUNK 80     // reordered cols per wg = 16 h * 5 gates
#define NH 16        // h-values per chunk
#define HCHUNKS 16   // 1280/80
#define WORKERS 16   // row-workers; worker w owns rows w, w+16, w+32
#define RING 4       // j-ring depth for S/C state
#define WLDS_STRIDE 520      // 512 + 8 pad
#define WLDS_STRIDE_PRE 264  // 256 + 8 pad
#define DSTRIDE 84           // 80 + 4 pad (Dl and Pxl staging)

// ---------------- pack / cast kernel ----------------
__global__ __launch_bounds__(256) void pack_kernel(
    const float* __restrict__ Wx, const float* __restrict__ Ws,
    const float* __restrict__ x, const float* __restrict__ y,
    __hip_bfloat16* __restrict__ Wxp, __hip_bfloat16* __restrict__ Wsp,
    __hip_bfloat16* __restrict__ xb, __hip_bfloat16* __restrict__ yb) {
  int idx = blockIdx.x * blockDim.x + threadIdx.x;
  int stride = gridDim.x * blockDim.x;
  int total_w = NG * KK;
  for (int t = idx; t < total_w; t += stride) {
    int np = t / KK, k = t % KK;
    int orig = (np % 5) * Hh + (np / 5);
    Wxp[t] = __float2bfloat16(Wx[k * NG + orig]);
    Wsp[t] = __float2bfloat16(Ws[k * NG + orig]);
  }
  int total_x = Bb * Ii * Ff;
  for (int t = idx; t < total_x; t += stride) {
    int f = t % Ff; int rest = t / Ff; int b = rest % Bb; int i = rest / Bb;
    xb[(i * Bb + b) * Ff + f] = __float2bfloat16(x[(b * Ii + i) * Ff + f]);
    yb[(i * Bb + b) * Ff + f] = __float2bfloat16(y[(b * Oo + i) * Ff + f]);
  }
}

// ---------------- precompute GEMM: Px[i][b][n'], Py[j][b][n'] ----------------
__global__ __launch_bounds__(256) void pregemm(
    const __hip_bfloat16* __restrict__ xb, const __hip_bfloat16* __restrict__ yb,
    const __hip_bfloat16* __restrict__ Wxp,
    float* __restrict__ Px, float* __restrict__ Py) {
  __shared__ __hip_bfloat16 Wl[CHUNK * WLDS_STRIDE_PRE];
  int wg = blockIdx.x;
  int isY = wg >= (Ii * HCHUNKS);
  int w = isY ? wg - Ii * HCHUNKS : wg;
  int mblk = w >> 4;
  int hc = w & 15;
  int n0 = hc * CHUNK;
  int koff = isY ? Ff : 0;
  int tid = threadIdx.x;
  for (int idx = tid; idx < CHUNK * (Ff / 8); idx += 256) {
    int cl = idx >> 5;
    int kb = (idx & 31) << 3;
    *(short8*)&Wl[cl * WLDS_STRIDE_PRE + kb] =
        *(const short8*)&Wxp[(n0 + cl) * KK + koff + kb];
  }
  __syncthreads();
  int wave = tid >> 6, lane = tid & 63;
  int lr = lane & 15, q = lane >> 4;
  const __hip_bfloat16* Arow = (isY ? yb : xb) + ((size_t)mblk * Bb + wave * 16 + lr) * Ff;
  floatx4 acc[5];
#pragma unroll
  for (int t = 0; t < 5; t++) acc[t] = (floatx4){0.f, 0.f, 0.f, 0.f};
#pragma unroll
  for (int ks = 0; ks < Ff / 32; ks++) {
    int k = ks * 32 + q * 8;
    short8 a = *(const short8*)(Arow + k);
#pragma unroll
    for (int t = 0; t < 5; t++) {
      short8 bfr = *(const short8*)&Wl[(t * 16 + lr) * WLDS_STRIDE_PRE + k];
      acc[t] = __builtin_amdgcn_mfma_f32_16x16x32_bf16(a, bfr, acc[t], 0, 0, 0);
    }
  }
  float* Pr = (isY ? Py : Px) + (size_t)mblk * Bb * NG + n0;
#pragma unroll
  for (int t = 0; t < 5; t++)
#pragma unroll
    for (int r = 0; r < 4; r++)
      Pr[(wave * 16 + q * 4 + r) * NG + t * 16 + lr] = acc[t][r];
}

// ---------------- coherence helpers (L2-bypassing, no cache-wide fences) ----
__device__ __forceinline__ void wait16(const int* p) {
  while (__hip_atomic_load(p, __ATOMIC_RELAXED, __HIP_MEMORY_SCOPE_AGENT) < HCHUNKS)
    __builtin_amdgcn_s_sleep(1);
}

// 16B bf16 A-fragment via two 8B agent-scope (L1/L2-bypass) loads
__device__ __forceinline__ short8 load8_sc(const __hip_bfloat16* p) {
  const unsigned long long* q = (const unsigned long long*)p;
  union { unsigned long long u[2]; short8 v; } r;
  r.u[0] = __hip_atomic_load(q,     __ATOMIC_RELAXED, __HIP_MEMORY_SCOPE_AGENT);
  r.u[1] = __hip_atomic_load(q + 1, __ATOMIC_RELAXED, __HIP_MEMORY_SCOPE_AGENT);
  return r.v;
}

__device__ __forceinline__ void store_bf16_sc(__hip_bfloat16* p, float f) {
  union { __hip_bfloat16 b; unsigned short u; } cv;
  cv.b = __float2bfloat16(f);
  __hip_atomic_store((unsigned short*)p, cv.u, __ATOMIC_RELAXED, __HIP_MEMORY_SCOPE_AGENT);
}

// ---------------- row-pipelined recurrent kernel ----------------
// 256 wgs = 16 row-workers x 16 hchunks, 1 wg/CU. Worker w processes rows
// w, w+16, w+32, each j=0..47 left-to-right. Per cell, waits (tid0 only):
//   done[i-1][j]  (vertical data dep: S row above + C above)
//   done[i][j-1]  (sibling hchunks' S slices of own row)
//   done[i+1][j-4] (WAR: depth-4 j-ring slot reuse; ~2 steps of slack)
// State exchanged via sc0sc1 (agent-scope) loads/stores -> no buffer_wbl2 /
// buffer_inv anywhere; Px/Py/Wsp stay L2-resident. Horizontal C is
// register-carried; Px(+row) lives in LDS for all 48 cells of a row.
__global__ __launch_bounds__(256) void lstm_row(
    const float* __restrict__ Px, const float* __restrict__ Py,
    const float* __restrict__ bias, const __hip_bfloat16* __restrict__ Wsp,
    __hip_bfloat16* __restrict__ Sring, float* __restrict__ Cring,
    const __hip_bfloat16* __restrict__ Szero,
    float* __restrict__ out, int* __restrict__ done) {
  __shared__ __hip_bfloat16 Wl[CHUNK * WLDS_STRIDE];  // 83,200 B
  __shared__ float Dl[Bb * DSTRIDE];                  // 21,504 B
  __shared__ float Pxl[Bb * DSTRIDE];                 // 21,504 B
  int wg = blockIdx.x;
  int worker = wg >> 4;
  int hc = wg & 15;
  int n0 = hc * CHUNK;
  int h0 = hc * NH;
  int tid = threadIdx.x;
  int wave = tid >> 6, lane = tid & 63;
  int lr = lane & 15, q = lane >> 4;
  int hl = tid & 15;            // fixed h-lane for elementwise phase
  int brow0 = tid >> 4;         // b for elementwise iter 0 (+16 per iter)

  // persistent Ws slice: 80 cols x 512 k
  for (int idx = tid; idx < CHUNK * (KK / 8); idx += 256) {
    int cl = idx >> 6;
    int kb = (idx & 63) << 3;
    *(short8*)&Wl[cl * WLDS_STRIDE + kb] = *(const short8*)&Wsp[(n0 + cl) * KK + kb];
  }
  float bv[5];
#pragma unroll
  for (int g = 0; g < 5; g++) bv[g] = bias[g * Hh + h0 + hl];

#pragma unroll 1
  for (int rr = 0; rr < 3; rr++) {
    int i = worker + rr * WORKERS;
    // ---- per-row: Px slice -> LDS (reused for 48 cells) ----
    for (int idx = tid; idx < Bb * CHUNK; idx += 256) {
      int b = idx / CHUNK, c = idx - b * CHUNK;
      Pxl[b * DSTRIDE + c] = Px[(size_t)i * Bb * NG + b * NG + n0 + c];
    }
    float cvreg[4];   // register-carried horizontal C state c(i, j-1)
#pragma unroll
    for (int it = 0; it < 4; it++) cvreg[it] = 0.f;

#pragma unroll 1
    for (int j = 0; j < Oo; j++) {
      // ---- prefetch Py slice (immutable, L2-cacheable) before the waits ----
      const float* PyR = Py + (size_t)j * Bb * NG + n0;
      float pyv[4][5];
#pragma unroll
      for (int it = 0; it < 4; it++) {
        int base = (brow0 + 16 * it) * NG + 5 * hl;
#pragma unroll
        for (int g = 0; g < 5; g++) pyv[it][g] = PyR[base + g];
      }
      // ---- waits: tid0 polls, barrier broadcasts ----
      if (tid == 0) {
        if (i > 0) wait16(done + (i - 1) * Oo + j);
        if (j > 0) wait16(done + i * Oo + (j - 1));
        if (i + 1 < Ii && j >= RING) wait16(done + (i + 1) * Oo + (j - RING));
      }
      __syncthreads();   // also covers Pxl writes (j==0) and Dl reuse

      // ---- state pointers (depth-4 j-ring) ----
      const __hip_bfloat16* Sv = (i > 0)
          ? Sring + ((size_t)(i - 1) * RING + (j & (RING - 1))) * (Bb * Hh) : Szero;
      const __hip_bfloat16* Sh = (j > 0)
          ? Sring + ((size_t)i * RING + ((j - 1) & (RING - 1))) * (Bb * Hh) : Szero;
      __hip_bfloat16* Sout = Sring + ((size_t)i * RING + (j & (RING - 1))) * (Bb * Hh);
      float* Cout = Cring + ((size_t)i * RING + (j & (RING - 1))) * (Bb * Hh);

      // ---- C-above loads (agent scope), overlap with GEMM ----
      float chv[4];
      if (i > 0) {
        const float* Chp = Cring + ((size_t)(i - 1) * RING + (j & (RING - 1))) * (Bb * Hh);
#pragma unroll
        for (int it = 0; it < 4; it++)
          chv[it] = __hip_atomic_load(&Chp[(brow0 + 16 * it) * Hh + h0 + hl],
                                      __ATOMIC_RELAXED, __HIP_MEMORY_SCOPE_AGENT);
      } else {
#pragma unroll
        for (int it = 0; it < 4; it++) chv[it] = 0.f;
      }

      // ---- GEMM: (64 x 512) @ (512 x 80); A = [S_above | S_left] ----
      const __hip_bfloat16* SvR = Sv + (size_t)(wave * 16 + lr) * Hh;
      const __hip_bfloat16* ShR = Sh + (size_t)(wave * 16 + lr) * Hh;
      floatx4 acc[5];
#pragma unroll
      for (int t = 0; t < 5; t++) acc[t] = (floatx4){0.f, 0.f, 0.f, 0.f};
#pragma unroll
      for (int ks = 0; ks < KK / 32; ks++) {
        int k = ks * 32 + q * 8;
        short8 a = (k < Hh) ? load8_sc(SvR + k) : load8_sc(ShR + (k - Hh));
#pragma unroll
        for (int t = 0; t < 5; t++) {
          short8 bfr = *(const short8*)&Wl[(t * 16 + lr) * WLDS_STRIDE + k];
          acc[t] = __builtin_amdgcn_mfma_f32_16x16x32_bf16(a, bfr, acc[t], 0, 0, 0);
        }
      }
      // ---- stage D (C-layout: col=lane&15, row=(lane>>4)*4+r) to LDS ----
#pragma unroll
      for (int t = 0; t < 5; t++)
#pragma unroll
        for (int r = 0; r < 4; r++)
          Dl[(wave * 16 + q * 4 + r) * DSTRIDE + t * 16 + lr] = acc[t][r];
      __syncthreads();
      // ---- elementwise LSTM update: 64 b x 16 h ----
#pragma unroll
      for (int it = 0; it < 4; it++) {
        int b = brow0 + 16 * it;
        float pre[5];
#pragma unroll
        for (int g = 0; g < 5; g++)
          pre[g] = Dl[b * DSTRIDE + 5 * hl + g] + Pxl[b * DSTRIDE + 5 * hl + g]
                 + pyv[it][g] + bv[g];
        float ig = 1.f / (1.f + __expf(-pre[0]));
        float fg = 1.f / (1.f + __expf(-pre[1]));
        float og = 1.f / (1.f + __expf(-pre[2]));
        float lg = 1.f / (1.f + __expf(-pre[3]));
        float gg = 1.f - 2.f / (__expf(2.f * pre[4]) + 1.f);   // tanh
        float cn = fg * (lg * chv[it] + (1.f - lg) * cvreg[it]) + ig * gg;
        float tc = 1.f - 2.f / (__expf(2.f * cn) + 1.f);
        float sn = og * tc;
        cvreg[it] = cn;                      // horizontal C for cell (i, j+1)
        int h = h0 + hl;
        __hip_atomic_store(&Cout[b * Hh + h], cn,
                           __ATOMIC_RELAXED, __HIP_MEMORY_SCOPE_AGENT);
        store_bf16_sc(&Sout[b * Hh + h], sn);
        out[(((size_t)i * Oo + j) * Bb + b) * Hh + h] = sn;
      }
      // ---- publish: drain wg stores (vmcnt(0) implied by barrier), bump flag
      __syncthreads();
      if (tid == 0) atomicAdd(done + i * Oo + j, 1);
    }
  }
}

// ---------------- host ----------------
extern "C" void kernel_launch(void* const* d_in, const int* in_sizes, int n_in,
                              void* d_out, int out_size, void* d_ws, size_t ws_size,
                              hipStream_t stream) {
  const float* x    = (const float*)d_in[0];
  const float* y    = (const float*)d_in[1];
  const float* Wx   = (const float*)d_in[2];
  const float* Ws   = (const float*)d_in[3];
  const float* bias = (const float*)d_in[4];
  float* out = (float*)d_out;

  char* ws = (char*)d_ws;
  size_t off = 0;
  auto alloc = [&](size_t bytes) -> void* {
    void* p = ws + off;
    off += (bytes + 255) & ~(size_t)255;
    return p;
  };
  __hip_bfloat16* Wxp = (__hip_bfloat16*)alloc((size_t)NG * KK * 2);
  __hip_bfloat16* Wsp = (__hip_bfloat16*)alloc((size_t)NG * KK * 2);
  __hip_bfloat16* xb  = (__hip_bfloat16*)alloc((size_t)Ii * Bb * Ff * 2);
  __hip_bfloat16* yb  = (__hip_bfloat16*)alloc((size_t)Oo * Bb * Ff * 2);
  float* Px = (float*)alloc((size_t)Ii * Bb * NG * 4);
  float* Py = (float*)alloc((size_t)Oo * Bb * NG * 4);
  __hip_bfloat16* Sring = (__hip_bfloat16*)alloc((size_t)Ii * RING * Bb * Hh * 2);
  float* Cring = (float*)alloc((size_t)Ii * RING * Bb * Hh * 4);
  char* zbase = ws + off;
  __hip_bfloat16* Szero = (__hip_bfloat16*)alloc((size_t)Bb * Hh * 2);
  int*   done = (int*)alloc((size_t)Ii * Oo * 4);
  size_t zBytes = (size_t)((ws + off) - zbase);

  // only the zero-buffer + flags need zeroing (ring slots are written before
  // any read per the dependency order)
  hipMemsetAsync(zbase, 0, zBytes, stream);

  hipLaunchKernelGGL(pack_kernel, dim3(512), dim3(256), 0, stream,
                     Wx, Ws, x, y, Wxp, Wsp, xb, yb);
  hipLaunchKernelGGL(pregemm, dim3(2 * Ii * HCHUNKS), dim3(256), 0, stream,
                     xb, yb, Wxp, Px, Py);

  void* args[] = {(void*)&Px, (void*)&Py, (void*)&bias, (void*)&Wsp,
                  (void*)&Sring, (void*)&Cring, (void*)&Szero,
                  (void*)&out, (void*)&done};
  hipLaunchCooperativeKernel((void*)lstm_row, dim3(WORKERS * HCHUNKS), dim3(256),
                             args, 0, stream);
}